// Round 5
// baseline (643.869 us; speedup 1.0000x reference)
//
#include <hip/hip_runtime.h>

typedef unsigned short ushort_t;
typedef __attribute__((ext_vector_type(8))) short short8;
typedef __attribute__((ext_vector_type(4))) float f32x4;
typedef __attribute__((ext_vector_type(4))) float vf4;

// Problem constants (fixed by the reference)
constexpr int N_ATOMS = 50000;
constexpr int N_EDGES = 800000;
constexpr int ELEM    = 64;
constexpr int D_IN    = 192;   // 2*ELEM + NBR
constexpr int D_OUT   = 128;   // 2*ELEM
constexpr float EPS   = 1e-5f;

constexpr int TILE_M  = 64;    // edges per GEMM tile
constexpr int N_TILES = N_EDGES / TILE_M;   // 12500
constexpr int NREP    = 16;    // stat-accumulator replicas

// Workspace layout (bytes), 16B-aligned. Total ~225 MB.
constexpr size_t OFF_NS   = 0;                                        // f32 ns[N][64]
constexpr size_t OFF_ABF  = OFF_NS   + (size_t)N_ATOMS * ELEM * 4;    // bf16 atom_bf[N][64]
constexpr size_t OFF_WT   = OFF_ABF  + (size_t)N_ATOMS * ELEM * 2;    // bf16 Wt[128][192]
constexpr size_t OFF_BN1  = OFF_WT   + (size_t)D_OUT * D_IN * 2;      // f32 [NREP][256]
constexpr size_t OFF_SC1  = OFF_BN1  + NREP * 256 * 4;                // f32 [256]
constexpr size_t OFF_BN2  = OFF_SC1  + 256 * 4;                       // f32 [NREP][128]
constexpr size_t OFF_T2   = OFF_BN2  + NREP * 128 * 4;                // bf16 T2[tile][128][64]

__device__ __forceinline__ ushort_t f32_to_bf16(float f) {
    unsigned int u = __float_as_uint(f);
    u = (u + 0x7fffu + ((u >> 16) & 1u)) >> 16;   // RNE
    return (ushort_t)u;
}
__device__ __forceinline__ float bf16_to_f32(ushort_t h) {
    return __uint_as_float(((unsigned int)h) << 16);
}
__device__ __forceinline__ float softplus_f(float x) {
    return fmaxf(x, 0.f) + __logf(1.f + __expf(-fabsf(x)));
}

// ---- 0: prep + init: atom->bf16, W->Wt (bf16 transposed), zero ns + replicas ----
__global__ void prep_init_kernel(const float* __restrict__ atom, const float* __restrict__ W,
                                 ushort_t* __restrict__ abf, ushort_t* __restrict__ Wt,
                                 float* __restrict__ ns,
                                 float* __restrict__ bn1r, float* __restrict__ bn2r) {
    int i = blockIdx.x * blockDim.x + threadIdx.x;
    if (i < N_ATOMS * ELEM) { abf[i] = f32_to_bf16(atom[i]); ns[i] = 0.f; }
    if (i < D_IN * D_OUT) {
        int k = i >> 7, n = i & 127;                 // coalesced read of W[k][n]
        Wt[n * D_IN + k] = f32_to_bf16(W[i]);
    }
    if (i < NREP * 256) bn1r[i] = 0.f;
    if (i < NREP * 128) bn2r[i] = 0.f;
}

// gathered atom rows into As chunks 0/1 (128B/row, 8 threads/row)
__device__ __forceinline__ void stage_atoms(ushort_t (*As)[200],
                                            const ushort_t* __restrict__ abf,
                                            const int* __restrict__ sidx,
                                            const int* __restrict__ nidx,
                                            int e0, int tid) {
    #pragma unroll
    for (int ch = 0; ch < 2; ++ch) {
        const int* __restrict__ idx = ch ? nidx : sidx;
        #pragma unroll
        for (int i = 0; i < 2; ++i) {
            int r = (tid >> 3) + 32 * i;
            int h = tid & 7;
            const uint4* src = (const uint4*)(abf + (size_t)idx[e0 + r] * 64);
            *(uint4*)&As[r][ch * 64 + h * 8] = src[h];
        }
    }
}

// ---- 1: stats pass — gather+MFMA, col sum/sumsq from regs; store T2 (no bias:
//         BN's batch mean absorbs the linear bias exactly, so it is dropped) ----
// T2 layout: [tile][col(128)][row(64)] bf16 — column-contiguous for the msg pass,
// and writable straight from the accumulator fragments (4 consecutive rows/lane).
__global__ __launch_bounds__(256) void stats_kernel(
    const ushort_t* __restrict__ abf, const float* __restrict__ nbrf,
    const int* __restrict__ sidx, const int* __restrict__ nidx,
    const ushort_t* __restrict__ Wt,
    ushort_t* __restrict__ T2, float* __restrict__ bn1r)
{
    __shared__ __align__(16) ushort_t As[64][200];   // 25.6 KB
    const int tid = threadIdx.x;
    const int e0  = blockIdx.x * TILE_M;

    stage_atoms(As, abf, sidx, nidx, e0, tid);
    // chunk 2: nbrf fp32 (nontemporal: single use, keep T2 in LLC) -> bf16 LDS
    #pragma unroll
    for (int i = 0; i < 4; ++i) {
        int r  = (tid >> 4) + 16 * i;
        int c4 = tid & 15;
        vf4 v = __builtin_nontemporal_load((const vf4*)(nbrf + (size_t)(e0 + r) * 64 + c4 * 4));
        ushort4 pk;
        pk.x = f32_to_bf16(v.x); pk.y = f32_to_bf16(v.y);
        pk.z = f32_to_bf16(v.z); pk.w = f32_to_bf16(v.w);
        *(ushort4*)&As[r][128 + c4 * 4] = pk;
    }

    const int wave = tid >> 6, lane = tid & 63;
    const int m16 = lane & 15, quad = lane >> 4;

    f32x4 acc[4][2];
    #pragma unroll
    for (int mt = 0; mt < 4; ++mt)
        #pragma unroll
        for (int nt = 0; nt < 2; ++nt) acc[mt][nt] = (f32x4){0.f, 0.f, 0.f, 0.f};

    const ushort_t* bp0 = Wt + (size_t)(wave * 32 + m16) * D_IN + quad * 8;
    const ushort_t* bp1 = bp0 + 16 * D_IN;

    __syncthreads();

    // K in two halves of 3x32 to cap bfrag register pressure
    #pragma unroll
    for (int h = 0; h < 2; ++h) {
        short8 b0[3], b1[3];
        #pragma unroll
        for (int ks = 0; ks < 3; ++ks) {
            b0[ks] = *(const short8*)(bp0 + (h * 3 + ks) * 32);
            b1[ks] = *(const short8*)(bp1 + (h * 3 + ks) * 32);
        }
        #pragma unroll
        for (int ks = 0; ks < 3; ++ks) {
            int ko = (h * 3 + ks) * 32 + quad * 8;
            #pragma unroll
            for (int mt = 0; mt < 4; ++mt) {
                short8 a = *(const short8*)&As[mt * 16 + m16][ko];
                acc[mt][0] = __builtin_amdgcn_mfma_f32_16x16x32_bf16(a, b0[ks], acc[mt][0], 0, 0, 0);
                acc[mt][1] = __builtin_amdgcn_mfma_f32_16x16x32_bf16(a, b1[ks], acc[mt][1], 0, 0, 0);
            }
        }
    }

    // store T2 straight from regs: lane has rows mt*16+quad*4+[0..4) of col c
    ushort_t* tp = T2 + (size_t)blockIdx.x * 128 * 64;
    #pragma unroll
    for (int nt = 0; nt < 2; ++nt) {
        int c = wave * 32 + nt * 16 + m16;
        #pragma unroll
        for (int mt = 0; mt < 4; ++mt) {
            uint2 u;
            u.x = (unsigned)f32_to_bf16(acc[mt][nt][0]) | ((unsigned)f32_to_bf16(acc[mt][nt][1]) << 16);
            u.y = (unsigned)f32_to_bf16(acc[mt][nt][2]) | ((unsigned)f32_to_bf16(acc[mt][nt][3]) << 16);
            *(uint2*)&tp[c * 64 + mt * 16 + quad * 4] = u;
        }
    }

    // per-lane partial col stats over its 16 rows, butterfly over quad, atomics
    float* rep = bn1r + (size_t)(blockIdx.x & (NREP - 1)) * 256;
    #pragma unroll
    for (int nt = 0; nt < 2; ++nt) {
        int c = wave * 32 + nt * 16 + m16;
        float s = 0.f, q = 0.f;
        #pragma unroll
        for (int mt = 0; mt < 4; ++mt)
            #pragma unroll
            for (int r = 0; r < 4; ++r) {
                float v = acc[mt][nt][r];
                s += v; q += v * v;
            }
        s += __shfl_xor(s, 16); s += __shfl_xor(s, 32);
        q += __shfl_xor(q, 16); q += __shfl_xor(q, 32);
        if (quad == 0) {
            atomicAdd(&rep[c], s);
            atomicAdd(&rep[128 + c], q);
        }
    }
}

// ---- 2: finalize BN1 -> per-column scale/shift (bias dropped: mean absorbs it) ----
__global__ void bn1_finalize(const float* __restrict__ bn1r,
                             const float* __restrict__ g1, const float* __restrict__ b1,
                             float* __restrict__ sc) {
    int c = threadIdx.x;   // 128
    float s = 0.f, q = 0.f;
    #pragma unroll
    for (int r = 0; r < NREP; ++r) { s += bn1r[r * 256 + c]; q += bn1r[r * 256 + 128 + c]; }
    float mean = s * (1.f / N_EDGES);
    float var  = q * (1.f / N_EDGES) - mean * mean;
    float scale = g1[c] * rsqrtf(var + EPS);
    sc[c] = scale;
    sc[128 + c] = b1[c] - mean * scale;
}

// ---- 3: msg pass — stream T2 (LLC-hot), gate in regs, segment-sum. No GEMM. ----
// One wave per tile; lane c holds filter col c and core col 64+c (contiguous 128B each).
__global__ __launch_bounds__(256) void msg_kernel(
    const ushort_t* __restrict__ T2, const int* __restrict__ sidx,
    const float* __restrict__ sc, float* __restrict__ ns)
{
    __shared__ int ss[256];   // 4 tiles x 64 sidx
    const int tid  = threadIdx.x;
    const int wave = tid >> 6, lane = tid & 63;
    const int tile = blockIdx.x * 4 + wave;
    const int e0   = tile * TILE_M;

    ss[tid] = sidx[blockIdx.x * 256 + tid];

    const ushort_t* fp = T2 + (size_t)tile * 128 * 64 + lane * 64;         // filter col
    const ushort_t* cp = fp + 64 * 64;                                      // core col
    float scf = sc[lane],      shf = sc[128 + lane];
    float scc = sc[64 + lane], shc = sc[192 + lane];

    __syncthreads();

    const int* sst = ss + wave * 64;
    int cur = sst[0];
    float acc = 0.f;
    #pragma unroll
    for (int ch = 0; ch < 8; ++ch) {
        uint4 fv = *(const uint4*)(fp + ch * 8);   // 8 rows filter
        uint4 cv = *(const uint4*)(cp + ch * 8);   // 8 rows core
        const unsigned* fw = (const unsigned*)&fv;
        const unsigned* cw = (const unsigned*)&cv;
        #pragma unroll
        for (int j = 0; j < 8; ++j) {
            int r = ch * 8 + j;
            int s = sst[r];                        // wave-uniform LDS broadcast
            if (s != cur) {
                atomicAdd(&ns[(size_t)cur * 64 + lane], acc);
                cur = s; acc = 0.f;
            }
            unsigned wf = fw[j >> 1], wc = cw[j >> 1];
            float tf = (j & 1) ? __uint_as_float(wf & 0xffff0000u)
                               : __uint_as_float(wf << 16);
            float tc = (j & 1) ? __uint_as_float(wc & 0xffff0000u)
                               : __uint_as_float(wc << 16);
            float yf = fmaf(tf, scf, shf);
            float yc = fmaf(tc, scc, shc);
            acc += softplus_f(yc) / (1.f + __expf(-yf));
        }
    }
    atomicAdd(&ns[(size_t)cur * 64 + lane], acc);
}

// ---- 4: BN2 column stats (replicated atomics) ----
__global__ __launch_bounds__(256) void bn2_stats_kernel(
    const float* __restrict__ ns, float* __restrict__ bn2r)
{
    int c = threadIdx.x & 63;
    float s = 0.f, q = 0.f;
    for (int a = blockIdx.x * 4 + (threadIdx.x >> 6); a < N_ATOMS; a += 4096) {
        float v = ns[a * ELEM + c];
        s += v; q += v * v;
    }
    float* rep = bn2r + (size_t)(blockIdx.x & (NREP - 1)) * 128;
    atomicAdd(&rep[c], s);
    atomicAdd(&rep[64 + c], q);
}

// ---- 5: BN2 finalize (folded, per-block) + affine + residual + softplus ----
__global__ __launch_bounds__(256) void final_kernel(
    const float* __restrict__ atom, const float* __restrict__ ns,
    const float* __restrict__ bn2r, const float* __restrict__ g2,
    const float* __restrict__ b2, float* __restrict__ out)
{
    __shared__ float sc2s[128];
    int t = threadIdx.x;
    if (t < 64) {
        float s = 0.f, q = 0.f;
        #pragma unroll
        for (int r = 0; r < NREP; ++r) { s += bn2r[r * 128 + t]; q += bn2r[r * 128 + 64 + t]; }
        float mean = s * (1.f / N_ATOMS);
        float var  = q * (1.f / N_ATOMS) - mean * mean;
        float scale = g2[t] * rsqrtf(var + EPS);
        sc2s[t] = scale;
        sc2s[64 + t] = b2[t] - mean * scale;
    }
    __syncthreads();
    int i = blockIdx.x * 256 + t;
    if (i < N_ATOMS * ELEM) {
        int c = t & 63;
        float x = atom[i] + fmaf(ns[i], sc2s[c], sc2s[64 + c]);
        out[i] = softplus_f(x);
    }
}

extern "C" void kernel_launch(void* const* d_in, const int* in_sizes, int n_in,
                              void* d_out, int out_size, void* d_ws, size_t ws_size,
                              hipStream_t stream) {
    const float* atom = (const float*)d_in[0];
    const float* nbrf = (const float*)d_in[1];
    const int*   sidx = (const int*)d_in[2];
    const int*   nidx = (const int*)d_in[3];
    const float* W    = (const float*)d_in[4];
    // d_in[5] (bias) intentionally unused: batch-norm's batch mean cancels it.
    const float* g1   = (const float*)d_in[6];
    const float* b1   = (const float*)d_in[7];
    const float* g2   = (const float*)d_in[8];
    const float* b2   = (const float*)d_in[9];
    float* out = (float*)d_out;
    char*  ws  = (char*)d_ws;

    float*    ns    = (float*)(ws + OFF_NS);
    ushort_t* abf   = (ushort_t*)(ws + OFF_ABF);
    ushort_t* Wt    = (ushort_t*)(ws + OFF_WT);
    float*    bn1r  = (float*)(ws + OFF_BN1);
    float*    sc1   = (float*)(ws + OFF_SC1);
    float*    bn2r  = (float*)(ws + OFF_BN2);
    ushort_t* T2    = (ushort_t*)(ws + OFF_T2);

    hipLaunchKernelGGL(prep_init_kernel, dim3((N_ATOMS * ELEM + 255) / 256), dim3(256), 0, stream,
                       atom, W, abf, Wt, ns, bn1r, bn2r);
    hipLaunchKernelGGL(stats_kernel, dim3(N_TILES), dim3(256), 0, stream,
                       abf, nbrf, sidx, nidx, Wt, T2, bn1r);
    hipLaunchKernelGGL(bn1_finalize, dim3(1), dim3(128), 0, stream, bn1r, g1, b1, sc1);
    hipLaunchKernelGGL(msg_kernel, dim3(N_TILES / 4), dim3(256), 0, stream,
                       T2, sidx, sc1, ns);
    hipLaunchKernelGGL(bn2_stats_kernel, dim3(1024), dim3(256), 0, stream, ns, bn2r);
    hipLaunchKernelGGL(final_kernel, dim3((N_ATOMS * ELEM + 255) / 256), dim3(256), 0, stream,
                       atom, ns, bn2r, g2, b2, out);
}